// Round 4
// baseline (30.222 us; speedup 1.0000x reference)
//
#include <hip/hip_runtime.h>

#define EPSV 1e-4f

// One cyclic-Jacobi rotation for the symmetric 3x3, pair (p,q), other index r.
__device__ __forceinline__ void jrot(float& app, float& aqq, float& apq,
                                     float& arp, float& arq,
                                     float& vap, float& vaq,
                                     float& vbp, float& vbq,
                                     float& vcp, float& vcq) {
  const float apq0 = apq;
  float tau = (aqq - app) / (2.0f * apq0);               // may be inf/nan if apq0==0
  float t = copysignf(1.0f / (fabsf(tau) + sqrtf(fmaf(tau, tau, 1.0f))), tau);
  if (apq0 == 0.0f) t = 0.0f;                            // covers the nan case too
  const float c = rsqrtf(fmaf(t, t, 1.0f));
  const float s = t * c;
  const float d = t * apq0;
  app -= d; aqq += d; apq = 0.0f;
  const float rp = arp, rq = arq;
  arp = c * rp - s * rq;
  arq = s * rp + c * rq;
  float x, y;
  x = vap; y = vaq; vap = c * x - s * y; vaq = s * x + c * y;
  x = vbp; y = vbq; vbp = c * x - s * y; vbq = s * x + c * y;
  x = vcp; y = vcq; vcp = c * x - s * y; vcq = s * x + c * y;
}

// Pair-lane single-phase layout: each wave handles 32 elements; lanes l and
// l+32 redundantly compute element (l&31)'s eigendecomposition and split the
// 81 outputs by column block (j<5 vs j>=5). Value-gen and LDS writes are
// full-wave (no exec masking), ONE staging phase, one store burst, no WAR
// wait. launch_bounds(256,2) caps VGPR at 256 (spill-proof, round-2 lesson);
// LDS (41.7KB -> 3 blocks/CU = 12 waves/CU) stays the occupancy limit.
__global__ __launch_bounds__(256, 2) void spd_decoder_kernel(
    const float* __restrict__ vech, const float* __restrict__ W1,
    const float* __restrict__ W2, const float* __restrict__ W3,
    float* __restrict__ out, int B) {
  __shared__ float Tsh[21];                 // W2@W1 (7x3)
  __shared__ float Msh[27];                 // W3@W2@W1 (9x3)
  __shared__ __align__(16) float buf[4][2592];  // per-wave staging (32 elem * 81)

  const int tid = threadIdx.x;

  // ---- per-block precompute of M = W3@W2@W1 ----
  if (tid < 21) {
    const int r = tid / 3, c = tid % 3;
    float acc = 0.f;
#pragma unroll
    for (int j = 0; j < 5; ++j) acc += W2[r * 5 + j] * W1[j * 3 + c];
    Tsh[tid] = acc;
  }
  __syncthreads();
  if (tid < 27) {
    const int r = tid / 3, c = tid % 3;
    float acc = 0.f;
#pragma unroll
    for (int j = 0; j < 7; ++j) acc += W3[r * 7 + j] * Tsh[j * 3 + c];
    Msh[tid] = acc;
  }
  __syncthreads();

  const int w = tid >> 6, l = tid & 63;
  const int q = l & 31;            // element slot within wave
  const int hi = l >> 5;           // column-block selector (0: j=0..4, 1: j=5..8)

  // ---- load vech (pair lanes duplicate the load), build symmetric 3x3 ----
  const int e = blockIdx.x * 128 + w * 32 + q;   // 128 elements per block
  const float2* vp = reinterpret_cast<const float2*>(vech + (size_t)e * 6);
  const float2 p0 = vp[0], p1 = vp[1], p2 = vp[2];
  float a00 = p0.x, a01 = p0.y, a02 = p1.x, a11 = p1.y, a12 = p2.x, a22 = p2.y;

  // ---- 3x3 Jacobi eigendecomposition, V accumulated ----
  float v00 = 1.f, v01 = 0.f, v02 = 0.f;
  float v10 = 0.f, v11 = 1.f, v12 = 0.f;
  float v20 = 0.f, v21 = 0.f, v22 = 1.f;
#pragma unroll
  for (int sweep = 0; sweep < 5; ++sweep) {
    jrot(a00, a11, a01, a02, a12, v00, v01, v10, v11, v20, v21);  // (0,1), r=2
    jrot(a00, a22, a02, a01, a12, v00, v02, v10, v12, v20, v22);  // (0,2), r=1
    jrot(a11, a22, a12, a01, a02, v01, v02, v11, v12, v21, v22);  // (1,2), r=0
  }

  const float e0 = expf(a00) - EPSV;
  const float e1 = expf(a11) - EPSV;
  const float e2 = expf(a22) - EPSV;

  // ---- g_k = M v_k; out(i,j) = sum_k e_k g_k[i] g_k[j] + eps*delta_ij ----
  float g0[9], g1[9], g2[9];
#pragma unroll
  for (int i = 0; i < 9; ++i) {
    const float m0 = Msh[i * 3 + 0], m1 = Msh[i * 3 + 1], m2 = Msh[i * 3 + 2];
    g0[i] = fmaf(m0, v00, fmaf(m1, v10, m2 * v20));
    g1[i] = fmaf(m0, v01, fmaf(m1, v11, m2 * v21));
    g2[i] = fmaf(m0, v02, fmaf(m1, v12, m2 * v22));
  }

  // shifted column views: h_k[jl] = g_k[jl + 5*hi]  (jl=4 only used by hi=0)
  float h0[5], h1[5], h2[5];
#pragma unroll
  for (int jl = 0; jl < 4; ++jl) {
    h0[jl] = hi ? g0[jl + 5] : g0[jl];
    h1[jl] = hi ? g1[jl + 5] : g1[jl];
    h2[jl] = hi ? g2[jl + 5] : g2[jl];
  }
  h0[4] = g0[4]; h1[4] = g1[4]; h2[4] = g2[4];
  const float epslo = hi ? 0.f : EPSV;   // diag add when j==i and i<5
  const float epshi = hi ? EPSV : 0.f;   // diag add when j==i and i>=5

  // ---- full-wave value-gen + LDS write (45 ds_write issues, all banks 2-way
  // max = free: lower/upper word addrs are 17q+c and 17q+c+5 mod 32) ----
  float* dst = &buf[w][q * 81 + hi * 5];
#pragma unroll
  for (int i = 0; i < 9; ++i) {
    const float t0 = e0 * g0[i], t1 = e1 * g1[i], t2 = e2 * g2[i];
#pragma unroll
    for (int jl = 0; jl < 5; ++jl) {
      float val = fmaf(t0, h0[jl], fmaf(t1, h1[jl], t2 * h2[jl]));
      if (i == jl) val += epslo;           // compile-time i==jl test
      if (i == jl + 5) val += epshi;       // compile-time test
      if (jl < 4) {
        dst[i * 9 + jl] = val;             // full-wave write
      } else if (!hi) {
        dst[i * 9 + 4] = val;              // lower-half-only column j=4
      }
    }
  }

  // writes landed before any lane's reads (wave-local wait, no vmcnt)
  asm volatile("s_waitcnt lgkmcnt(0)" ::: "memory");
  __builtin_amdgcn_sched_barrier(0);

  // ---- one coalesced store burst: 2592 floats = 648 float4 per wave ----
  const size_t eb = (size_t)(blockIdx.x * 128 + w * 32) * 81;
  const float4* rbuf = reinterpret_cast<const float4*>(&buf[w][0]);
  float4* outv = reinterpret_cast<float4*>(out + eb);
#pragma unroll
  for (int it = 0; it < 10; ++it) outv[it * 64 + l] = rbuf[it * 64 + l];
  if (l < 8) outv[640 + l] = rbuf[640 + l];  // 648 float4 total
}

extern "C" void kernel_launch(void* const* d_in, const int* in_sizes, int n_in,
                              void* d_out, int out_size, void* d_ws, size_t ws_size,
                              hipStream_t stream) {
  const float* vech = (const float*)d_in[0];
  const float* W1 = (const float*)d_in[1];
  const float* W2 = (const float*)d_in[2];
  const float* W3 = (const float*)d_in[3];
  float* out = (float*)d_out;
  const int B = in_sizes[0] / 6;  // 262144
  dim3 grid(B / 128), block(256);
  hipLaunchKernelGGL(spd_decoder_kernel, grid, block, 0, stream,
                     vech, W1, W2, W3, out, B);
}

// Round 6
// 24.460 us; speedup vs baseline: 1.2355x; 1.2355x over previous
//
#include <hip/hip_runtime.h>

#define EPSV 1e-4f

typedef float v4f __attribute__((ext_vector_type(4)));  // native vec for nt-store

// One cyclic-Jacobi rotation for the symmetric 3x3, pair (p,q), other index r.
__device__ __forceinline__ void jrot(float& app, float& aqq, float& apq,
                                     float& arp, float& arq,
                                     float& vap, float& vaq,
                                     float& vbp, float& vbq,
                                     float& vcp, float& vcq) {
  const float apq0 = apq;
  float tau = (aqq - app) / (2.0f * apq0);               // may be inf/nan if apq0==0
  float t = copysignf(1.0f / (fabsf(tau) + sqrtf(fmaf(tau, tau, 1.0f))), tau);
  if (apq0 == 0.0f) t = 0.0f;                            // covers the nan case too
  const float c = rsqrtf(fmaf(t, t, 1.0f));
  const float s = t * c;
  const float d = t * apq0;
  app -= d; aqq += d; apq = 0.0f;
  const float rp = arp, rq = arq;
  arp = c * rp - s * rq;
  arq = s * rp + c * rq;
  float x, y;
  x = vap; y = vaq; vap = c * x - s * y; vaq = s * x + c * y;
  x = vbp; y = vbq; vbp = c * x - s * y; vbq = s * x + c * y;
  x = vcp; y = vcq; vcp = c * x - s * y; vcq = s * x + c * y;
}

// Round-5 structure (recompiled): 4 phases of 16 elements -> LDS 21KB/block
// -> launch_bounds(256,4) gives 16 waves/CU (vs 12). Only the cross-lane RAW
// fence is kept (per-wave DS is in-order, so WAR across phase reuse is safe
// without a wait); no sched pinning, so the compiler may interleave
// next-phase valgen under store issue. Output stores are nontemporal
// (write-once data, bypass L2 write-allocate).
__global__ __launch_bounds__(256, 4) void spd_decoder_kernel(
    const float* __restrict__ vech, const float* __restrict__ W1,
    const float* __restrict__ W2, const float* __restrict__ W3,
    float* __restrict__ out, int B) {
  __shared__ float Tsh[21];                      // W2@W1 (7x3)
  __shared__ float Msh[27];                      // W3@W2@W1 (9x3)
  __shared__ __align__(16) float buf[4][1296];   // per-wave staging (16 elem * 81)

  const int tid = threadIdx.x;

  // ---- per-block precompute of M = W3@W2@W1 ----
  if (tid < 21) {
    const int r = tid / 3, c = tid % 3;
    float acc = 0.f;
#pragma unroll
    for (int j = 0; j < 5; ++j) acc += W2[r * 5 + j] * W1[j * 3 + c];
    Tsh[tid] = acc;
  }
  __syncthreads();
  if (tid < 27) {
    const int r = tid / 3, c = tid % 3;
    float acc = 0.f;
#pragma unroll
    for (int j = 0; j < 7; ++j) acc += W3[r * 7 + j] * Tsh[j * 3 + c];
    Msh[tid] = acc;
  }
  __syncthreads();

  // ---- load vech, build symmetric 3x3 ----
  const int e = blockIdx.x * 256 + tid;     // B is a multiple of 256
  const float2* vp = reinterpret_cast<const float2*>(vech + (size_t)e * 6);
  const float2 p0 = vp[0], p1 = vp[1], p2 = vp[2];
  float a00 = p0.x, a01 = p0.y, a02 = p1.x, a11 = p1.y, a12 = p2.x, a22 = p2.y;

  // ---- 3x3 Jacobi eigendecomposition, V accumulated ----
  float v00 = 1.f, v01 = 0.f, v02 = 0.f;
  float v10 = 0.f, v11 = 1.f, v12 = 0.f;
  float v20 = 0.f, v21 = 0.f, v22 = 1.f;
#pragma unroll
  for (int sweep = 0; sweep < 5; ++sweep) {
    jrot(a00, a11, a01, a02, a12, v00, v01, v10, v11, v20, v21);  // (0,1), r=2
    jrot(a00, a22, a02, a01, a12, v00, v02, v10, v12, v20, v22);  // (0,2), r=1
    jrot(a11, a22, a12, a01, a02, v01, v02, v11, v12, v21, v22);  // (1,2), r=0
  }

  const float e0 = expf(a00) - EPSV;
  const float e1 = expf(a11) - EPSV;
  const float e2 = expf(a22) - EPSV;

  // ---- g_k = M v_k; values generated on the fly in the store phases:
  // out(i,j) = e0 g0i g0j + e1 g1i g1j + e2 g2i g2j + eps*delta_ij ----
  float g0[9], g1[9], g2[9];
#pragma unroll
  for (int i = 0; i < 9; ++i) {
    const float m0 = Msh[i * 3 + 0], m1 = Msh[i * 3 + 1], m2 = Msh[i * 3 + 2];
    g0[i] = fmaf(m0, v00, fmaf(m1, v10, m2 * v20));
    g1[i] = fmaf(m0, v01, fmaf(m1, v11, m2 * v21));
    g2[i] = fmaf(m0, v02, fmaf(m1, v12, m2 * v22));
  }

  const int w = tid >> 6, l = tid & 63;
  float* wbuf = &buf[w][0];
  const size_t base = (size_t)(blockIdx.x * 256 + w * 64) * 81;

#pragma unroll
  for (int h = 0; h < 4; ++h) {
    if ((l >> 4) == h) {                 // quarter-wave writer group
      const int ll = l & 15;
      float* dst = wbuf + ll * 81;       // word stride 81 mod 32 = 17: 16 lanes
                                         // hit 16 distinct banks (17 odd)
#pragma unroll
      for (int i = 0; i < 9; ++i) {
        const float t0 = e0 * g0[i], t1 = e1 * g1[i], t2 = e2 * g2[i];
#pragma unroll
        for (int j = 0; j < 9; ++j) {
          float val = fmaf(t0, g0[j], fmaf(t1, g1[j], t2 * g2[j]));
          if (i == j) val += EPSV;       // compile-time branch after unroll
          dst[i * 9 + j] = val;
        }
      }
    }
    // cross-lane RAW: writes of this phase land before any lane reads them.
    // (WAR across the buffer reuse needs no wait: per-wave DS is in-order.)
    asm volatile("s_waitcnt lgkmcnt(0)" ::: "memory");

    // 1296 contiguous floats = 324 float4, nontemporal (write-once stream)
    const size_t sb = base + (size_t)h * 1296;
    const v4f* rbuf = reinterpret_cast<const v4f*>(wbuf);
    v4f* outv = reinterpret_cast<v4f*>(out + sb);
#pragma unroll
    for (int it = 0; it < 5; ++it)
      __builtin_nontemporal_store(rbuf[it * 64 + l], outv + it * 64 + l);
    if (l < 4) __builtin_nontemporal_store(rbuf[320 + l], outv + 320 + l);
  }
}

extern "C" void kernel_launch(void* const* d_in, const int* in_sizes, int n_in,
                              void* d_out, int out_size, void* d_ws, size_t ws_size,
                              hipStream_t stream) {
  const float* vech = (const float*)d_in[0];
  const float* W1 = (const float*)d_in[1];
  const float* W2 = (const float*)d_in[2];
  const float* W3 = (const float*)d_in[3];
  float* out = (float*)d_out;
  const int B = in_sizes[0] / 6;  // 262144
  dim3 grid(B / 256), block(256);
  hipLaunchKernelGGL(spd_decoder_kernel, grid, block, 0, stream,
                     vech, W1, W2, W3, out, B);
}